// Round 9
// baseline (104.126 us; speedup 1.0000x reference)
//
#include <hip/hip_runtime.h>
#include <hip/hip_bf16.h>

#define BATCH 16
#define SEQ 2048
#define DIM 64

typedef __attribute__((ext_vector_type(8))) __bf16 bf16x8;
typedef __attribute__((ext_vector_type(8))) unsigned short u16x8;
typedef __attribute__((ext_vector_type(2))) unsigned int u32x2;
typedef __attribute__((ext_vector_type(4))) unsigned int u32x4;
typedef __attribute__((ext_vector_type(16))) float f32x16;

#if __has_builtin(__builtin_amdgcn_exp2f)
#define EXP2F(x) __builtin_amdgcn_exp2f(x)
#else
#define EXP2F(x) __expf(0.69314718055994531f * (x))
#endif

__device__ __forceinline__ unsigned short f2bf_hw(float f) {
    __bf16 h = (__bf16)f;
    return __builtin_bit_cast(unsigned short, h);
}

__device__ __forceinline__ unsigned int pk_bf16(float lo, float hi) {
    unsigned int a = f2bf_hw(lo), b = f2bf_hw(hi);
    return a | (b << 16);
}

// half_swap(A,B) -> lo = {A.lanes[0:31], B.lanes[0:31] in upper lanes},
//                   hi = {A.lanes[32:63] in lower lanes, B.lanes[32:63]}.
__device__ __forceinline__ void half_swap(unsigned int a, unsigned int b,
                                          unsigned int& lo, unsigned int& hi) {
#if __has_builtin(__builtin_amdgcn_permlane32_swap)
    u32x2 r = __builtin_amdgcn_permlane32_swap(a, b, false, false);
    lo = r[0];
    hi = r[1];
#else
    unsigned int sa = (unsigned int)__shfl_xor((int)a, 32);
    unsigned int sb = (unsigned int)__shfl_xor((int)b, 32);
    const bool hh = (threadIdx.x & 32) != 0;
    lo = hh ? sb : a;
    hi = hh ? b : sa;
#endif
}

// Preconvert K and V to bf16 in fragment-order tile layout (R16, bit-identical
// output, 1024 blocks, XCD-matched).
// K tile (b,t): [g 8][key 128][8 shorts], element = K[b][t*128+key][(g>>1)*16+(g&1)*8+j]
// V tile (b,t): [g 16][d 64][8 shorts],  element = V[b][t*128+(g>>1)*16+(g&1)*8+j][d]
__global__ __launch_bounds__(256)
void preconvert_kv(const float* __restrict__ K, const float* __restrict__ V,
                   unsigned short* __restrict__ Ks, unsigned short* __restrict__ Vts) {
    __shared__ float vt[64 * 65];
    const int tid = threadIdx.x;
    const int x = blockIdx.x;
    const int b = ((x & 7) << 1) | ((x >> 3) & 1);
    const int kpath = (x >> 4) & 1;
    const int t = (x >> 5) & 15;
    const int half = (x >> 9) & 1;
    if (kpath) {
        const float* src = K + ((size_t)(b * SEQ + t * 128)) * DIM;
        unsigned short* dst = Ks + ((size_t)(b * 16 + t)) * 8192;
        #pragma unroll
        for (int p = 0; p < 2; ++p) {
            const int cid = p * 256 + tid;
            const int key = half * 64 + (cid >> 3), g = cid & 7;
            const int d0 = (g >> 1) * 16 + (g & 1) * 8;
            float4 x0 = *(const float4*)(src + key * DIM + d0);
            float4 x1 = *(const float4*)(src + key * DIM + d0 + 4);
            u16x8 o;
            o[0] = f2bf_hw(x0.x); o[1] = f2bf_hw(x0.y); o[2] = f2bf_hw(x0.z); o[3] = f2bf_hw(x0.w);
            o[4] = f2bf_hw(x1.x); o[5] = f2bf_hw(x1.y); o[6] = f2bf_hw(x1.z); o[7] = f2bf_hw(x1.w);
            *(u16x8*)(dst + (g * 128 + key) * 8) = o;
        }
    } else {
        const float* src = V + ((size_t)(b * SEQ + t * 128 + half * 64)) * DIM;
        #pragma unroll
        for (int p = 0; p < 4; ++p) {
            const int f = p * 256 + tid;
            const int row = f >> 4, c4 = (f & 15) << 2;
            float4 xv = *(const float4*)(src + row * DIM + c4);
            vt[row * 65 + c4 + 0] = xv.x; vt[row * 65 + c4 + 1] = xv.y;
            vt[row * 65 + c4 + 2] = xv.z; vt[row * 65 + c4 + 3] = xv.w;
        }
        __syncthreads();
        unsigned short* dst = Vts + ((size_t)(b * 16 + t)) * 8192;
        #pragma unroll
        for (int p = 0; p < 2; ++p) {
            const int cid = p * 256 + tid;
            const int gl = cid >> 6, d = cid & 63;
            const int g = half * 8 + gl;
            const int k0 = (g >> 1) * 16 + (g & 1) * 8 - half * 64;
            u16x8 o;
            #pragma unroll
            for (int j = 0; j < 8; ++j) o[j] = f2bf_hw(vt[(k0 + j) * 65 + d]);
            *(u16x8*)(dst + (g * 64 + d) * 8) = o;
        }
    }
}

// R17: cross-wave LDS-shared KV, 2 blocks/CU.
// Characterized trap (R9-R16): 2-qset regs pinned at 256 cap (prefetch dies,
// +regs spill); 1-qset direct-load halves compute-per-load (R12 wash); LDS at
// 1 block/CU exposes barriers (R15). This quadrant: 512 blocks x 4 waves
// (2 blocks/CU -> co-resident block covers barrier waits), waves = 2 q-subsets
// x 2 key-halves. Each key-half's wave PAIR stages its 32-key subtile (K 4KB +
// V 4KB) once into a 3-slot LDS ring (prefetch depth 2; loads issued BEFORE
// the barrier so they stay in flight across it). Consumers read fragments from
// LDS with the exact same index algebra as the verified global layout; compute
// kernels (calc_s/exp_swap/pv/epilogue) are the verified R12 single-set code.
// Per wave-phase: 4 global loads (was 8) + 8 ds_reads + 8 MFMA -> ~150 VGPR
// with real slack. Split-K/2 combine through LDS (ring reused as comb).
__global__ __launch_bounds__(256, 2)
void attn_flash_kernel(const float* __restrict__ Q,
                       const unsigned short* __restrict__ Ks,
                       const unsigned short* __restrict__ Vts,
                       const float* __restrict__ scaling,
                       float* __restrict__ O) {
    __shared__ __attribute__((aligned(16))) unsigned short ring[2][3][4096]; // 48 KB

    const int tid  = threadIdx.x;
    const int w    = tid >> 6;
    const int lane = tid & 63;
    const int m    = lane & 31;
    const int h    = lane >> 5;
    const int kh   = w >> 1;        // key-half 0..1
    const int qs   = w & 1;         // q-subset 0..1

    // XCD-aware swizzle: 2 batches per XCD
    const int x  = blockIdx.x;
    const int b  = ((x & 7) << 1) | ((x >> 3) & 1);
    const int q0 = (x >> 4) * 64;

    const float csc = 1.4426950408889634f / scaling[0];  // log2(e)/sqrt(D)

    // Q fragments: lane (m,h) holds Q[q0+qs*32+m][c*16+h*8+{0..7}]*csc
    bf16x8 aq[4];
    {
        const float* qsrc = Q + ((size_t)(b * SEQ + q0 + qs * 32 + m)) * DIM + h * 8;
        #pragma unroll
        for (int c = 0; c < 4; ++c) {
            float4 x0 = *(const float4*)(qsrc + c * 16);
            float4 x1 = *(const float4*)(qsrc + c * 16 + 4);
            u32x4 pk;
            pk[0] = pk_bf16(x0.x * csc, x0.y * csc);
            pk[1] = pk_bf16(x0.z * csc, x0.w * csc);
            pk[2] = pk_bf16(x1.x * csc, x1.y * csc);
            pk[3] = pk_bf16(x1.z * csc, x1.w * csc);
            aq[c] = __builtin_bit_cast(bf16x8, pk);
        }
    }

    f32x16 Oacc[2];
    #pragma unroll
    for (int dt = 0; dt < 2; ++dt)
        #pragma unroll
        for (int r = 0; r < 16; ++r) Oacc[dt][r] = 0.f;
    float psum = 0.f;

    // key-half kh covers tiles [kh*8, kh*8+8) of batch b (keys kh*1024 ..)
    const unsigned short* Kbh = Ks  + ((size_t)(b * 16 + kh * 8)) * 8192;
    const unsigned short* Vbh = Vts + ((size_t)(b * 16 + kh * 8)) * 8192;

    // staging: pair-lane L in [0,128) over the 2 waves of this key-half;
    // chunks i0=2L, i1=2L+1 of 16B; K chunk i: g=i>>5, mm=i&31;
    // V chunk i: q=i>>5 -> (c2,hh,dd)=(q>>2,(q>>1)&1,q&1).
    const int L  = qs * 64 + lane;
    const int i0 = 2 * L, i1 = 2 * L + 1;
    const int g0 = i0 >> 5, mk0 = i0 & 31;
    const int g1 = i1 >> 5, mk1 = i1 & 31;
    const int c20 = g0 >> 2, hh0 = (g0 >> 1) & 1, dd0 = g0 & 1;
    const int c21 = g1 >> 2, hh1 = (g1 >> 1) & 1, dd1 = g1 & 1;

    u16x8 rk0, rk1, rv0, rv1;
    auto load_sub = [&](int s) {
        const int it = s >> 2, tt = s & 3;
        const unsigned short* Kt = Kbh + (size_t)it * 8192;
        const unsigned short* Vt = Vbh + (size_t)it * 8192;
        rk0 = *(const u16x8*)(Kt + (g0 * 128 + tt * 32 + mk0) * 8);
        rk1 = *(const u16x8*)(Kt + (g1 * 128 + tt * 32 + mk1) * 8);
        rv0 = *(const u16x8*)(Vt + (((2 * tt + c20) * 2 + hh0) * 64 + dd0 * 32 + mk0) * 8);
        rv1 = *(const u16x8*)(Vt + (((2 * tt + c21) * 2 + hh1) * 64 + dd1 * 32 + mk1) * 8);
    };
    auto st_sub = [&](int slot) {
        unsigned short* base = &ring[kh][slot][0];
        *(u16x8*)(base + i0 * 8) = rk0;
        *(u16x8*)(base + i1 * 8) = rk1;
        *(u16x8*)(base + 2048 + i0 * 8) = rv0;
        *(u16x8*)(base + 2048 + i1 * 8) = rv1;
    };
    // consumers: identical index algebra to the verified global-layout loads
    auto ld_kc = [&](int slot, bf16x8* kc) {
        #pragma unroll
        for (int c = 0; c < 4; ++c)
            kc[c] = __builtin_bit_cast(bf16x8,
                *(const u16x8*)(&ring[kh][slot][((c * 2 + h) * 32 + m) * 8]));
    };
    auto ld_bv = [&](int slot, bf16x8 (*bv)[2]) {
        #pragma unroll
        for (int c2 = 0; c2 < 2; ++c2)
            #pragma unroll
            for (int dt = 0; dt < 2; ++dt)
                bv[c2][dt] = __builtin_bit_cast(bf16x8,
                    *(const u16x8*)(&ring[kh][slot][2048 + ((c2 * 4 + h * 2 + dt) * 32 + m) * 8]));
    };
    auto barrier_phase = [&]() {
        asm volatile("s_waitcnt lgkmcnt(0)" ::: "memory");
        __builtin_amdgcn_sched_barrier(0);
        __builtin_amdgcn_s_barrier();
        __builtin_amdgcn_sched_barrier(0);
    };

    // ---- prologue: stage subtiles 0,1; leave 2's loads in flight ----
    load_sub(0); st_sub(0);
    load_sub(1); st_sub(1);
    load_sub(2);
    barrier_phase();

    int sl = 0, ws = 2;
    #pragma unroll 1
    for (int t = 0; t < 32; ++t) {
        // compute subtile t from LDS
        bf16x8 kc[4];
        ld_kc(sl, kc);
        f32x16 S;
        #pragma unroll
        for (int r = 0; r < 16; ++r) S[r] = 0.f;
        #pragma unroll
        for (int c = 0; c < 4; ++c)
            S = __builtin_amdgcn_mfma_f32_32x32x16_bf16(kc[c], aq[c], S, 0, 0, 0);

        bf16x8 bv[2][2];
        ld_bv(sl, bv);

        unsigned int d0[8];
        #pragma unroll
        for (int k = 0; k < 4; ++k) {
            float a0 = EXP2F(S[4 * k + 0]), a1 = EXP2F(S[4 * k + 1]);
            float a2 = EXP2F(S[4 * k + 2]), a3 = EXP2F(S[4 * k + 3]);
            psum += (a0 + a1) + (a2 + a3);
            d0[2 * k + 0] = pk_bf16(a0, a1);
            d0[2 * k + 1] = pk_bf16(a2, a3);
        }
        bf16x8 pb[2];
        #pragma unroll
        for (int c2 = 0; c2 < 2; ++c2) {
            u32x4 bw;
            unsigned int lo, hi;
            half_swap(d0[4 * c2 + 0], d0[4 * c2 + 2], lo, hi);
            bw[0] = lo; bw[2] = hi;
            half_swap(d0[4 * c2 + 1], d0[4 * c2 + 3], lo, hi);
            bw[1] = lo; bw[3] = hi;
            pb[c2] = __builtin_bit_cast(bf16x8, bw);
        }
        __builtin_amdgcn_s_setprio(1);
        #pragma unroll
        for (int c2 = 0; c2 < 2; ++c2)
            #pragma unroll
            for (int dt = 0; dt < 2; ++dt)
                Oacc[dt] = __builtin_amdgcn_mfma_f32_32x32x16_bf16(bv[c2][dt], pb[c2], Oacc[dt], 0, 0, 0);
        __builtin_amdgcn_s_setprio(0);

        // write subtile t+2 (its loads flew across the last barrier; the
        // compiler inserts the vmcnt wait on rg here), then issue t+3 loads
        // so they stay in flight across the coming barrier.
        st_sub(ws);
        const int s3 = (t + 3 < 32) ? t + 3 : 31;
        load_sub(s3);
        barrier_phase();

        sl = (sl == 2) ? 0 : sl + 1;
        ws = (ws == 2) ? 0 : ws + 1;
    }

    // ---- combine 2 key-halves through LDS (ring reused), normalize, store ----
    float l = psum + __shfl_xor(psum, 32);
    float* C = (float*)&ring[0][0][0];     // 2*64*33 floats = 16.9 KB
    if (kh == 1) {
        float* dst = C + (qs * 64 + lane) * 33;
        #pragma unroll
        for (int dt = 0; dt < 2; ++dt)
            #pragma unroll
            for (int r = 0; r < 16; ++r)
                dst[dt * 16 + r] = Oacc[dt][r];
        dst[32] = l;
    }
    __syncthreads();
    if (kh == 0) {
        const float* src = C + (qs * 64 + lane) * 33;
        const float invl = 1.0f / (l + src[32]);
        float* orow = O + ((size_t)(b * SEQ + q0 + qs * 32 + m)) * DIM;
        #pragma unroll
        for (int dt = 0; dt < 2; ++dt) {
            #pragma unroll
            for (int k = 0; k < 4; ++k) {
                float4 o4;
                #pragma unroll
                for (int j = 0; j < 4; ++j) {
                    const int r = 4 * k + j;
                    ((float*)&o4)[j] = (Oacc[dt][r] + src[dt * 16 + r]) * invl;
                }
                *(float4*)(orow + dt * 32 + 8 * k + 4 * h) = o4;
            }
        }
    }
}

extern "C" void kernel_launch(void* const* d_in, const int* in_sizes, int n_in,
                              void* d_out, int out_size, void* d_ws, size_t ws_size,
                              hipStream_t stream) {
    const float* Q = (const float*)d_in[0];
    const float* K = (const float*)d_in[1];
    const float* V = (const float*)d_in[2];
    const float* scaling = (const float*)d_in[3];
    float* O = (float*)d_out;

    unsigned short* Ks  = (unsigned short*)d_ws;                  // 4 MB
    unsigned short* Vts = Ks + (size_t)BATCH * 16 * 8192;         // 4 MB

    preconvert_kv<<<dim3(1024), dim3(256), 0, stream>>>(K, V, Ks, Vts);
    attn_flash_kernel<<<dim3(BATCH * (SEQ / 64)), dim3(256), 0, stream>>>(Q, Ks, Vts, scaling, O);
}